// Round 14
// baseline (54.856 us; speedup 1.0000x reference)
//
#include <hip/hip_runtime.h>

// Problem constants (fixed by reference setup_inputs)
#define NB 32
#define NC 128
#define NH 63
#define NW 63
#define HW 3969          // 63*63
#define OH 30            // (63-5)/2+1
#define SEGW 11          // band cols per segment (4 tiles: x0=0..6 -> cols 0..10)
#define POSN 55          // 5*SEGW
#define NSEG 8           // tiles 4g..4g+3 (g=7: tiles 28,29 valid; 30,31 masked)
#define NBLK (NB*OH*NSEG)   // 7680

typedef _Float16 half2_t __attribute__((ext_vector_type(2)));
__device__ __forceinline__ half2_t u2h(unsigned u) { return __builtin_bit_cast(half2_t, u); }
__device__ __forceinline__ unsigned h2u(half2_t h) { return __builtin_bit_cast(unsigned, h); }

// 2-way fp16 dot with fp32 accumulate (v_dot2_f32_f16); exact-unpack fallback.
__device__ __forceinline__ float dot2(unsigned a, unsigned b, float c) {
#if __has_builtin(__builtin_amdgcn_fdot2)
    return __builtin_amdgcn_fdot2(u2h(a), u2h(b), c, false);
#else
    const half2_t x = u2h(a), y = u2h(b);
    c = fmaf((float)x[0], (float)y[0], c);
    return fmaf((float)x[1], (float)y[1], c);
#endif
}

__device__ __forceinline__ unsigned pk16(float a, float b) {
#if __has_builtin(__builtin_amdgcn_cvt_pkrtz)
    return __builtin_bit_cast(unsigned, __builtin_amdgcn_cvt_pkrtz(a, b));
#else
    const half2_t h = {(_Float16)a, (_Float16)b};
    return h2u(h);
#endif
}

// One block per (b, oi, 4-tile segment). Stages raw f as packed fp16, exact fp32
// norms in stager registers, S = sum_q f_q*inv_q (packed half2), and
// s[p] = 1 - (1/25)*(f_p . S)*inv_p (v_dot2_f32_f16).
// Band granule swizzle: logical uint4-granule gl of row pos at ((gl+pos)&15),
// applied identically on write and read.
// NOTE: bare launch_bounds -- min-waves clause collapses VGPR budget and spills.
__global__ __launch_bounds__(256) void seg_fused(const float* __restrict__ f,
                                                 float* __restrict__ slots) {
    // XCD-chunked swizzle (bijective: 7680 = 8*960): consecutive logical blocks =
    // the 8 segments of one strip, then adjacent strips -> same-XCD L2 reuse.
    const int lb    = (blockIdx.x & 7) * (NBLK / 8) + (blockIdx.x >> 3);
    const int strip = lb >> 3, g = lb & 7;
    const int b = strip / OH, oi = strip % OH;
    const int y0 = oi * 2, xlo = 8 * g;
    const int t = threadIdx.x;

    __shared__ unsigned band[POSN * 64];   // 14080 B: [pos][64 uints = 128 fp16]
    __shared__ float sq4[POSN][4];         // per-pos sumsq quarters
    __shared__ float sinv[POSN];           // fp32 inv-norm per pos
    __shared__ unsigned sinvh[POSN];       // inv as splatted half2
    __shared__ uint4 Slh[16][4];           // per-(slot, tile) S as 8 half2
    __shared__ float wmax[4];

    // ---- stage: t<220 -> (pos = t%55, quarter q = t/55 -> 32 channels) ----
    if (t < 4 * POSN) {
        const int pos = t % POSN, q = t / POSN;
        const int r = pos / SEGW, xx = pos % SEGW;
        const int x = xlo + xx;
        float ss = 0.0f;
        if (x < NW) {
            const float* gp = f + (size_t)b * NC * HW + (size_t)(q * 32) * HW
                                + (size_t)(y0 + r) * NW + x;
            #pragma unroll
            for (int ch = 0; ch < 2; ++ch) {
                float v[16];
                #pragma unroll
                for (int k = 0; k < 16; ++k) v[k] = gp[(size_t)(ch * 16 + k) * HW];
                #pragma unroll
                for (int k = 0; k < 16; ++k) ss = fmaf(v[k], v[k], ss);
                unsigned u[8];
                #pragma unroll
                for (int j = 0; j < 8; ++j) u[j] = pk16(v[2 * j], v[2 * j + 1]);
                const int g0 = 4 * q + 2 * ch;        // logical uint4-granule
                *(uint4*)&band[pos * 64 + (((g0     + pos) & 15) << 2)] =
                    make_uint4(u[0], u[1], u[2], u[3]);
                *(uint4*)&band[pos * 64 + (((g0 + 1 + pos) & 15) << 2)] =
                    make_uint4(u[4], u[5], u[6], u[7]);
            }
        } else {
            #pragma unroll
            for (int j = 0; j < 4; ++j)               // zero own granules (swizzled)
                *(uint4*)&band[pos * 64 + (((4 * q + j + pos) & 15) << 2)] =
                    make_uint4(0u, 0u, 0u, 0u);
        }
        sq4[pos][q] = ss;
    }
    __syncthreads();
    if (t < POSN) {
        const float s   = sq4[t][0] + sq4[t][1] + sq4[t][2] + sq4[t][3];
        const float inv = (s > 0.0f) ? rsqrtf(s) : 0.0f;
        sinv[t] = inv;
        const half2_t i2 = {(_Float16)inv, (_Float16)inv};
        sinvh[t] = h2u(i2);
    }
    __syncthreads();

    // ---- S-phase: t<64 -> (tl = t>>4, slot = t&15), s += f_q * inv_q ----
    if (t < 64) {
        const int tl = t >> 4, slot = t & 15;
        half2_t s0 = u2h(0u), s1 = u2h(0u), s2 = u2h(0u), s3 = u2h(0u);
        #pragma unroll
        for (int r = 0; r < 5; ++r)
            #pragma unroll
            for (int k = 0; k < 5; ++k) {
                const int pos = r * SEGW + 2 * tl + k;
                const uint4 v = *(const uint4*)&band[pos * 64 + (((slot + pos) & 15) << 2)];
                const half2_t iv = u2h(sinvh[pos]);
                s0 = u2h(v.x) * iv + s0;
                s1 = u2h(v.y) * iv + s1;
                s2 = u2h(v.z) * iv + s2;
                s3 = u2h(v.w) * iv + s3;
            }
        Slh[slot][tl] = make_uint4(h2u(s0), h2u(s1), h2u(s2), h2u(s3));
    }
    __syncthreads();

    // ---- dots: t<100, one (tile, p) item each ----
    float m = 0.0f;
    if (t < 100) {
        const int tl = t / 25, p = t % 25;
        if (4 * g + tl < OH) {
            const int pos = (p / 5) * SEGW + 2 * tl + (p % 5);
            float acc = 0.0f;
            #pragma unroll
            for (int slot = 0; slot < 16; ++slot) {
                const uint4 sv = Slh[slot][tl];
                const uint4 v  = *(const uint4*)&band[pos * 64 + (((slot + pos) & 15) << 2)];
                acc = dot2(v.x, sv.x, acc);
                acc = dot2(v.y, sv.y, acc);
                acc = dot2(v.z, sv.z, acc);
                acc = dot2(v.w, sv.w, acc);
            }
            m = fmaxf(0.0f, 1.0f - acc * sinv[pos] * 0.04f);
        }
    }
    #pragma unroll
    for (int off = 1; off < 64; off <<= 1) m = fmaxf(m, __shfl_xor(m, off));
    if ((t & 63) == 0) wmax[t >> 6] = m;
    __syncthreads();
    if (t == 0)
        slots[lb] = fmaxf(fmaxf(wmax[0], wmax[1]), fmaxf(wmax[2], wmax[3]));
}

// ---------------- finalize: 7680 slots -> loss ----------------
__global__ __launch_bounds__(256) void finalize(const float* __restrict__ slots,
                                                const int* __restrict__ label,
                                                float* __restrict__ out) {
    const int t = threadIdx.x;
    __shared__ float bmax[32];
    const int b = t >> 3, j = t & 7;          // 8 threads per b, 240 slots each
    float m = 0.0f;
    for (int i = j; i < 240; i += 8) m = fmaxf(m, slots[b * 240 + i]);
    m = fmaxf(m, __shfl_xor(m, 1));
    m = fmaxf(m, __shfl_xor(m, 2));
    m = fmaxf(m, __shfl_xor(m, 4));
    if (j == 0) bmax[b] = m;
    __syncthreads();
    if (t == 0) {
        float fs = 0.0f, rs = 0.0f, fc = 0.0f, rc = 0.0f;
        for (int b2 = 0; b2 < NB; ++b2) {
            const float tb  = bmax[b2];
            const float lbv = (float)label[b2];
            fs += tb * lbv;          fc += lbv;
            rs += tb * (1.0f - lbv); rc += (1.0f - lbv);
        }
        const float loss = 1.0f - fs / fc + rs / rc;
        out[0] = fmaxf(loss, 0.0f);
    }
}

extern "C" void kernel_launch(void* const* d_in, const int* in_sizes, int n_in,
                              void* d_out, int out_size, void* d_ws, size_t ws_size,
                              hipStream_t stream) {
    const float* feature = (const float*)d_in[0];
    const int* label     = (const int*)d_in[1];
    float* out   = (float*)d_out;
    float* slots = (float*)d_ws;   // 7680 floats, fully rewritten each launch

    seg_fused<<<NBLK, 256, 0, stream>>>(feature, slots);
    finalize<<<1, 256, 0, stream>>>(slots, label, out);
}

// Round 15
// 34.046 us; speedup vs baseline: 1.6112x; 1.6112x over previous
//
#include <hip/hip_runtime.h>

// Problem constants (fixed by reference setup_inputs)
#define NB 32
#define NC 128
#define NH 63
#define NW 63
#define HW 3969          // 63*63
#define OH 30            // (63-5)/2+1
#define SEGW 19          // band cols per segment (tiles 8g..8g+7 -> cols 16g..16g+18)
#define NROW 9           // 3 strips: rows y0..y0+8
#define POSN (NROW*SEGW) // 171
#define NSST 10          // superstrips per b (30 = 3*10)
#define NSEG 4
#define NBLK (NB*NSST*NSEG)  // 1280

typedef _Float16 half2_t __attribute__((ext_vector_type(2)));
__device__ __forceinline__ half2_t u2h(unsigned u) { return __builtin_bit_cast(half2_t, u); }
__device__ __forceinline__ unsigned h2u(half2_t h) { return __builtin_bit_cast(unsigned, h); }

__device__ __forceinline__ float dot2(unsigned a, unsigned b, float c) {
#if __has_builtin(__builtin_amdgcn_fdot2)
    return __builtin_amdgcn_fdot2(u2h(a), u2h(b), c, false);
#else
    const half2_t x = u2h(a), y = u2h(b);
    c = fmaf((float)x[0], (float)y[0], c);
    return fmaf((float)x[1], (float)y[1], c);
#endif
}

__device__ __forceinline__ unsigned pk16(float a, float b) {
#if __has_builtin(__builtin_amdgcn_cvt_pkrtz)
    return __builtin_bit_cast(unsigned, __builtin_amdgcn_cvt_pkrtz(a, b));
#else
    const half2_t h = {(_Float16)a, (_Float16)b};
    return h2u(h);
#endif
}

// One block per (b, 3-strip superstrip, 8-tile segment). 9 rows x 19 cols staged
// once serve 24 windows -> vertical read redundancy 2.38x -> 1.43x vs R13.
// One thread owns one position's full 128 channels: exact fp32 sumsq in regs,
// packed-fp16 band write, sinv written by the stager (no reduce phase).
// Band granule swizzle: logical uint4-granule gl of row pos at ((gl+pos)&15),
// identical on write and read (both-sides rule).
// NOTE: bare launch_bounds -- a min-waves clause collapses the VGPR budget and
// spills (R6: 2.6 GB scratch, R7: 58 MB scratch).
__global__ __launch_bounds__(256) void seg_fused(const float* __restrict__ f,
                                                 float* __restrict__ slots) {
    // XCD-chunked swizzle (bijective: 1280 = 8*160).
    const int lb  = (blockIdx.x & 7) * (NBLK / 8) + (blockIdx.x >> 3);
    const int b   = lb / (NSST * NSEG);
    const int rem = lb % (NSST * NSEG);
    const int sst = rem >> 2, g = rem & 3;
    const int y0 = 6 * sst, xlo = 16 * g;
    const int t = threadIdx.x;

    __shared__ unsigned band[POSN * 64];   // 43776 B: [pos][64 uints = 128 fp16]
    __shared__ float sinv[POSN];
    __shared__ unsigned sinvh[POSN];
    __shared__ uint4 Slh[16][24];          // 6144 B: per-(slot, tile) S as 8 half2
    __shared__ float wmax[3][4];

    // ---- stage: t<171 owns position t (all 128 channels) ----
    if (t < POSN) {
        const int r = t / SEGW, xx = t % SEGW;
        const int x = xlo + xx;
        float inv = 0.0f;
        if (x < NW) {
            const float* gp = f + (size_t)b * NC * HW + (size_t)(y0 + r) * NW + x;
            float ss = 0.0f;
            #pragma unroll
            for (int ch = 0; ch < 8; ++ch) {
                float v[16];
                #pragma unroll
                for (int k = 0; k < 16; ++k) v[k] = gp[(size_t)(ch * 16 + k) * HW];
                #pragma unroll
                for (int k = 0; k < 16; ++k) ss = fmaf(v[k], v[k], ss);
                unsigned u[8];
                #pragma unroll
                for (int j = 0; j < 8; ++j) u[j] = pk16(v[2 * j], v[2 * j + 1]);
                *(uint4*)&band[t * 64 + (((2 * ch     + t) & 15) << 2)] =
                    make_uint4(u[0], u[1], u[2], u[3]);
                *(uint4*)&band[t * 64 + (((2 * ch + 1 + t) & 15) << 2)] =
                    make_uint4(u[4], u[5], u[6], u[7]);
            }
            inv = (ss > 0.0f) ? rsqrtf(ss) : 0.0f;
        } else {
            #pragma unroll
            for (int j = 0; j < 16; ++j)
                *(uint4*)&band[t * 64 + (((j + t) & 15) << 2)] = make_uint4(0u, 0u, 0u, 0u);
        }
        sinv[t] = inv;
        const half2_t i2 = {(_Float16)inv, (_Float16)inv};
        sinvh[t] = h2u(i2);
    }
    __syncthreads();

    // ---- S-phase: 384 items (24 tiles x 16 slots); thread t does t and t+256 ----
    #pragma unroll
    for (int jj = 0; jj < 2; ++jj) {
        const int i = t + jj * 256;
        if (i < 384) {
            const int tl = i >> 4, slot = i & 15;
            const int s_ = tl >> 3, txx = tl & 7;
            half2_t s0 = u2h(0u), s1 = u2h(0u), s2 = u2h(0u), s3 = u2h(0u);
            #pragma unroll
            for (int pr = 0; pr < 5; ++pr)
                #pragma unroll
                for (int pc = 0; pc < 5; ++pc) {
                    const int pos = (2 * s_ + pr) * SEGW + 2 * txx + pc;
                    const uint4 v = *(const uint4*)&band[pos * 64 + (((slot + pos) & 15) << 2)];
                    const half2_t iv = u2h(sinvh[pos]);
                    s0 = u2h(v.x) * iv + s0;
                    s1 = u2h(v.y) * iv + s1;
                    s2 = u2h(v.z) * iv + s2;
                    s3 = u2h(v.w) * iv + s3;
                }
            Slh[slot][tl] = make_uint4(h2u(s0), h2u(s1), h2u(s2), h2u(s3));
        }
    }
    __syncthreads();

    // ---- dots: t<200 -> items {t, t+200, t+400} = strips {0,1,2} at pos+38j ----
    float m[3] = {0.0f, 0.0f, 0.0f};
    if (t < 200) {
        const int txx = t / 25, p = t % 25;
        if (8 * g + txx < OH) {
            const int pos0 = (p / 5) * SEGW + 2 * txx + (p % 5);
            #pragma unroll
            for (int j = 0; j < 3; ++j) {
                const int pos = pos0 + 2 * SEGW * j;
                const int tl  = 8 * j + txx;
                float acc = 0.0f;
                #pragma unroll
                for (int slot = 0; slot < 16; ++slot) {
                    const uint4 sv = Slh[slot][tl];
                    const uint4 v  = *(const uint4*)&band[pos * 64 + (((slot + pos) & 15) << 2)];
                    acc = dot2(v.x, sv.x, acc);
                    acc = dot2(v.y, sv.y, acc);
                    acc = dot2(v.z, sv.z, acc);
                    acc = dot2(v.w, sv.w, acc);
                }
                m[j] = fmaxf(0.0f, 1.0f - acc * sinv[pos] * 0.04f);
            }
        }
    }
    #pragma unroll
    for (int off = 1; off < 64; off <<= 1) {
        m[0] = fmaxf(m[0], __shfl_xor(m[0], off));
        m[1] = fmaxf(m[1], __shfl_xor(m[1], off));
        m[2] = fmaxf(m[2], __shfl_xor(m[2], off));
    }
    if ((t & 63) == 0) {
        wmax[0][t >> 6] = m[0];
        wmax[1][t >> 6] = m[1];
        wmax[2][t >> 6] = m[2];
    }
    __syncthreads();
    if (t < 3) {
        const float mm = fmaxf(fmaxf(wmax[t][0], wmax[t][1]),
                               fmaxf(wmax[t][2], wmax[t][3]));
        // slot layout [b][oi][g], oi = 3*sst + t
        slots[((b * OH) + 3 * sst + t) * 4 + g] = mm;
    }
}

// ---------------- finalize: 3840 slots -> loss ----------------
__global__ __launch_bounds__(128) void finalize(const float* __restrict__ slots,
                                                const int* __restrict__ label,
                                                float* __restrict__ out) {
    const int t = threadIdx.x;
    __shared__ float bmax[32];
    const int b = t >> 2, j = t & 3;          // 4 threads per b, 120 slots each
    float m = 0.0f;
    for (int i = j; i < 120; i += 4) m = fmaxf(m, slots[b * 120 + i]);
    m = fmaxf(m, __shfl_xor(m, 1));
    m = fmaxf(m, __shfl_xor(m, 2));
    if (j == 0) bmax[b] = m;
    __syncthreads();
    if (t == 0) {
        float fs = 0.0f, rs = 0.0f, fc = 0.0f, rc = 0.0f;
        for (int b2 = 0; b2 < NB; ++b2) {
            const float tb  = bmax[b2];
            const float lbv = (float)label[b2];
            fs += tb * lbv;          fc += lbv;
            rs += tb * (1.0f - lbv); rc += (1.0f - lbv);
        }
        const float loss = 1.0f - fs / fc + rs / rc;
        out[0] = fmaxf(loss, 0.0f);
    }
}

extern "C" void kernel_launch(void* const* d_in, const int* in_sizes, int n_in,
                              void* d_out, int out_size, void* d_ws, size_t ws_size,
                              hipStream_t stream) {
    const float* feature = (const float*)d_in[0];
    const int* label     = (const int*)d_in[1];
    float* out   = (float*)d_out;
    float* slots = (float*)d_ws;   // 3840 floats, fully rewritten each launch

    seg_fused<<<NBLK, 256, 0, stream>>>(feature, slots);
    finalize<<<1, 128, 0, stream>>>(slots, label, out);
}